// Round 13
// baseline (41307.050 us; speedup 1.0000x reference)
//
#include <hip/hip_runtime.h>
#include <stdint.h>

#define LAYERS    5
#define INPUT_DIM 512
#define CODE_DIM  2048
#define BATCH     32768
#define KSP       32

#define BM  128
#define BN  128
#define BKT 32

#define GLOAD_LDS16(dst, src) \
    __builtin_amdgcn_global_load_lds((const __attribute__((address_space(1))) uint32_t*)(src), \
                                     (__attribute__((address_space(3))) uint32_t*)(dst), 16, 0, 0)

// ---------------------------------------------------------------------------
// D [512][2048] -> Dt [2048][512]  (bit copy)
__global__ __launch_bounds__(256) void transpose_512x2048_kernel(const float* __restrict__ src,
                                                                 float* __restrict__ dst)
{
    __shared__ float tile[32][33];
    const int tx = threadIdx.x;
    const int ty = threadIdx.y;
    const int cb = blockIdx.x * 32;
    const int ib = blockIdx.y * 32;
    #pragma unroll
    for (int j = 0; j < 32; j += 8)
        tile[ty + j][tx] = src[(size_t)(ib + ty + j) * CODE_DIM + cb + tx];
    __syncthreads();
    #pragma unroll
    for (int j = 0; j < 32; j += 8)
        dst[(size_t)(cb + ty + j) * INPUT_DIM + ib + tx] = tile[tx][ty + j];
}

// ---------------------------------------------------------------------------
// u = x@Wl (+ z@Sl for l>0).  Arithmetic contract (np/BLAS-faithful):
//  - x@W: one f32 accumulator per element, k = 0..511 strictly ascending fmaf
//  - z@S: separate zero-init accumulator, 32 nz folded ascending-index, fmaf
//  - u = xw + zs (single add)
// r11 compute structure + DOUBLE-BUFFERED LDS (T14 issue-early/write-late):
//  per tile: issue next x-loads (named p0..p3) + gload_lds B(next buf) ->
//  compute current buf -> ds_write A(next buf) -> ONE barrier.
// Plain macro code, NO lambdas (r10 lesson: lambda staging -> 256 VGPR),
// acc/zacc only compile-time-indexed (r5/r6/r7 lessons), 8x8 tile max.
__global__ __launch_bounds__(256) void gemm_layer_kernel(
    const float* __restrict__ x, const float* __restrict__ Wl,
    const float* __restrict__ Sl, const int* __restrict__ zidx,
    const float* __restrict__ zval, float* __restrict__ u)
{
    __shared__ float As[2][BKT][BM];   // unpadded (reads broadcast, writes 2/bank)
    __shared__ float Bs[2][BKT][BN];   // gload dest; reads conflict-free
    // total 64 KB exactly

    const int t    = threadIdx.x;
    const int lane = t & 63;
    const int wid  = t >> 6;
    const int c0   = blockIdx.x * BN;
    const int r0   = blockIdx.y * BM;
    const int tm0  = (t >> 4) * 8;        // 8 rows
    const int cn   = (t & 15) * 4;        // col quads at cn, cn+64

    // A staging: thread owns one contiguous 64B chunk of its x row-half
    const int   arow = t >> 1;            // LDS row (m index)
    const int   ak   = (t & 1) * 16;      // k base within tile
    const float* xrow = x + (size_t)(r0 + arow) * INPUT_DIM;

    float4 p0, p1, p2, p3;                // in-flight A stage (16 VGPR)

#define PREFETCH_LOAD(KTN)                                                   \
    p0 = *(const float4*)&xrow[(KTN) + ak + 0];                              \
    p1 = *(const float4*)&xrow[(KTN) + ak + 4];                              \
    p2 = *(const float4*)&xrow[(KTN) + ak + 8];                              \
    p3 = *(const float4*)&xrow[(KTN) + ak + 12];

#define PREFETCH_B(B, KTN)                                                   \
    {                                                                        \
        _Pragma("unroll")                                                    \
        for (int s = 0; s < 4; ++s) {                                        \
            int rr = wid * 8 + s * 2;                                        \
            GLOAD_LDS16(&Bs[B][rr][0],                                       \
                Wl + (size_t)((KTN) + rr + (lane >> 5)) * CODE_DIM           \
                   + c0 + (lane & 31) * 4);                                  \
        }                                                                    \
    }

#define STAGE_A(B)                                                           \
    As[B][ak +  0][arow] = p0.x; As[B][ak +  1][arow] = p0.y;                \
    As[B][ak +  2][arow] = p0.z; As[B][ak +  3][arow] = p0.w;                \
    As[B][ak +  4][arow] = p1.x; As[B][ak +  5][arow] = p1.y;                \
    As[B][ak +  6][arow] = p1.z; As[B][ak +  7][arow] = p1.w;                \
    As[B][ak +  8][arow] = p2.x; As[B][ak +  9][arow] = p2.y;                \
    As[B][ak + 10][arow] = p2.z; As[B][ak + 11][arow] = p2.w;                \
    As[B][ak + 12][arow] = p3.x; As[B][ak + 13][arow] = p3.y;                \
    As[B][ak + 14][arow] = p3.z; As[B][ak + 15][arow] = p3.w;

#define COMPUTE_TILE(B)                                                      \
    _Pragma("unroll")                                                        \
    for (int kk = 0; kk < BKT; ++kk) {                                       \
        float av[8], bv[8];                                                  \
        *(float4*)&av[0] = *(const float4*)&As[B][kk][tm0];                  \
        *(float4*)&av[4] = *(const float4*)&As[B][kk][tm0 + 4];              \
        *(float4*)&bv[0] = *(const float4*)&Bs[B][kk][cn];                   \
        *(float4*)&bv[4] = *(const float4*)&Bs[B][kk][cn + 64];              \
        _Pragma("unroll")                                                    \
        for (int i = 0; i < 8; ++i)                                          \
            _Pragma("unroll")                                                \
            for (int j = 0; j < 8; ++j)                                      \
                acc[i][j] = fmaf(av[i], bv[j], acc[i][j]);                   \
    }

    float acc[8][8];
    #pragma unroll
    for (int i = 0; i < 8; ++i)
        #pragma unroll
        for (int j = 0; j < 8; ++j) acc[i][j] = 0.f;

    // prologue: tile 0 -> buf0
    PREFETCH_LOAD(0);
    PREFETCH_B(0, 0);
    STAGE_A(0);
    __syncthreads();

    for (int kt = 0; kt < INPUT_DIM; kt += 2 * BKT) {
        // half 1: prefetch tile kt+32 into buf1, compute buf0
        PREFETCH_LOAD(kt + BKT);
        PREFETCH_B(1, kt + BKT);
        COMPUTE_TILE(0);
        STAGE_A(1);
        __syncthreads();
        // half 2: prefetch tile kt+64 into buf0 (if any), compute buf1
        if (kt + 2 * BKT < INPUT_DIM) {
            PREFETCH_LOAD(kt + 2 * BKT);
            PREFETCH_B(0, kt + 2 * BKT);
        }
        COMPUTE_TILE(1);
        if (kt + 2 * BKT < INPUT_DIM) {
            STAGE_A(0);
        }
        __syncthreads();
    }

#undef PREFETCH_LOAD
#undef PREFETCH_B
#undef STAGE_A
#undef COMPUTE_TILE

    if (Sl != nullptr) {
        #pragma unroll
        for (int i = 0; i < 8; ++i) {           // FULLY unrolled: acc[i] static
            const int r = r0 + tm0 + i;
            const int*   ip = zidx + (size_t)r * KSP;   // ascending code index
            const float* vp = zval + (size_t)r * KSP;
            float zacc[8];
            #pragma unroll
            for (int j = 0; j < 8; ++j) zacc[j] = 0.f;
            for (int k = 0; k < KSP; ++k) {     // runtime k only touches memory
                int   j = ip[k];
                float v = vp[k];
                const float* srow = Sl + (size_t)j * CODE_DIM + c0 + cn;
                float4 s0 = *(const float4*)&srow[0];
                float4 s1 = *(const float4*)&srow[64];
                zacc[0] = fmaf(v, s0.x, zacc[0]);
                zacc[1] = fmaf(v, s0.y, zacc[1]);
                zacc[2] = fmaf(v, s0.z, zacc[2]);
                zacc[3] = fmaf(v, s0.w, zacc[3]);
                zacc[4] = fmaf(v, s1.x, zacc[4]);
                zacc[5] = fmaf(v, s1.y, zacc[5]);
                zacc[6] = fmaf(v, s1.z, zacc[6]);
                zacc[7] = fmaf(v, s1.w, zacc[7]);
            }
            #pragma unroll
            for (int j = 0; j < 8; ++j)     // single add: u = xw + zs
                acc[i][j] = acc[i][j] + zacc[j];
        }
    }

    #pragma unroll
    for (int i = 0; i < 8; ++i) {
        float* up = u + (size_t)(r0 + tm0 + i) * CODE_DIM + c0 + cn;
        *(float4*)&up[0]  = make_float4(acc[i][0], acc[i][1], acc[i][2], acc[i][3]);
        *(float4*)&up[64] = make_float4(acc[i][4], acc[i][5], acc[i][6], acc[i][7]);
    }
}

// ---------------------------------------------------------------------------
// top-32 by |u| (desc, tie -> lower index), one WAVE per row, registers only.
// Key-only max tree + ballot owner-select; keys = (|u| bits)+1 (monotone,
// 0 = popped sentinel).  All register arrays statically indexed (rule #20).
__global__ __launch_bounds__(256) void topk32_wave_kernel(const float* __restrict__ u,
                                                          int* __restrict__ zidx,
                                                          float* __restrict__ zval)
{
    const int lane = threadIdx.x & 63;
    const int row  = blockIdx.x * 4 + (threadIdx.x >> 6);
    const float* ur = u + (size_t)row * CODE_DIM;

    uint32_t a[32];                       // lane's keys: global idx = lane*32 + j
    #pragma unroll
    for (int q = 0; q < 8; ++q) {
        float4 v = *(const float4*)&ur[lane * 32 + q * 4];
        a[q * 4 + 0] = (__float_as_uint(v.x) & 0x7fffffffu) + 1u;
        a[q * 4 + 1] = (__float_as_uint(v.y) & 0x7fffffffu) + 1u;
        a[q * 4 + 2] = (__float_as_uint(v.z) & 0x7fffffffu) + 1u;
        a[q * 4 + 3] = (__float_as_uint(v.w) & 0x7fffffffu) + 1u;
    }

    uint32_t wi = 0xFFFFFFFFu;            // slot-it winner gidx (lanes 0..31)
    for (int it = 0; it < KSP; ++it) {
        uint32_t t0[16], t1[8], t2[4], t3[2];
        #pragma unroll
        for (int j = 0; j < 16; ++j) t0[j] = a[2*j]  > a[2*j+1]  ? a[2*j]  : a[2*j+1];
        #pragma unroll
        for (int j = 0; j < 8;  ++j) t1[j] = t0[2*j] > t0[2*j+1] ? t0[2*j] : t0[2*j+1];
        #pragma unroll
        for (int j = 0; j < 4;  ++j) t2[j] = t1[2*j] > t1[2*j+1] ? t1[2*j] : t1[2*j+1];
        #pragma unroll
        for (int j = 0; j < 2;  ++j) t3[j] = t2[2*j] > t2[2*j+1] ? t2[2*j] : t2[2*j+1];
        const uint32_t mloc = t3[0] > t3[1] ? t3[0] : t3[1];

        uint32_t g = mloc;
        #pragma unroll
        for (int off = 1; off <= 32; off <<= 1) {
            uint32_t og = __shfl_xor(g, off);
            g = og > g ? og : g;
        }

        unsigned long long bal = __ballot(mloc == g);
        int owner = __ffsll(bal) - 1;

        int bj = 0;
        #pragma unroll
        for (int j = 31; j >= 0; --j)
            if (a[j] == g) bj = j;
        int bjo = __shfl(bj, owner);

        uint32_t gidx = (uint32_t)owner * 32u + (uint32_t)bjo;
        if (lane == it) wi = gidx;

        if (lane == owner) {
            #pragma unroll
            for (int j = 0; j < 32; ++j)
                if (j == bjo) a[j] = 0u;
        }
    }

    int rank = 0;
    #pragma unroll
    for (int m = 0; m < 32; ++m) {
        uint32_t om = __shfl(wi, m);
        rank += (om < wi) ? 1 : 0;
    }
    if (lane < KSP) {
        int idx = (int)wi;
        zidx[(size_t)row * KSP + rank] = idx;
        zval[(size_t)row * KSP + rank] = ur[idx];
    }
}

// ---------------------------------------------------------------------------
__global__ __launch_bounds__(256) void zfill_scatter_kernel(const int* __restrict__ zidx,
                                                            const float* __restrict__ zval,
                                                            float* __restrict__ zden)
{
    const int t  = threadIdx.x;
    const int r0 = blockIdx.x * 8;
    float* base = zden + (size_t)r0 * CODE_DIM;
    const float4 zero = make_float4(0.f, 0.f, 0.f, 0.f);
    for (int q = t; q < 8 * CODE_DIM / 4; q += 256)
        *(float4*)&base[q * 4] = zero;
    __syncthreads();
    const int rl = t >> 5, k = t & 31;
    int   idx = zidx[(size_t)(r0 + rl) * KSP + k];
    float v   = zval[(size_t)(r0 + rl) * KSP + k];
    base[(size_t)rl * CODE_DIM + idx] = v;
}

// ---------------------------------------------------------------------------
// recon: ascending-index fold of 32 nonzeros, f32 fmaf (np z@D.T faithful)
__global__ __launch_bounds__(128) void recon_kernel(const int* __restrict__ zidx,
                                                    const float* __restrict__ zval,
                                                    const float* __restrict__ Dt,
                                                    float* __restrict__ recon)
{
    const int t   = threadIdx.x;
    const int row = blockIdx.x;
    float4 acc = make_float4(0.f, 0.f, 0.f, 0.f);
    const int*   ip = zidx + (size_t)row * KSP;
    const float* vp = zval + (size_t)row * KSP;
    for (int k = 0; k < KSP; ++k) {
        int   j = ip[k];
        float v = vp[k];
        float4 d = *(const float4*)&Dt[(size_t)j * INPUT_DIM + t * 4];
        acc.x = fmaf(v, d.x, acc.x);
        acc.y = fmaf(v, d.y, acc.y);
        acc.z = fmaf(v, d.z, acc.z);
        acc.w = fmaf(v, d.w, acc.w);
    }
    *(float4*)&recon[(size_t)row * INPUT_DIM + t * 4] = acc;
}

// ---------------------------------------------------------------------------
extern "C" void kernel_launch(void* const* d_in, const int* in_sizes, int n_in,
                              void* d_out, int out_size, void* d_ws, size_t ws_size,
                              hipStream_t stream)
{
    const float* x = (const float*)d_in[0];
    const float* W = (const float*)d_in[1];   // [5][512][2048]
    const float* S = (const float*)d_in[2];   // [5][2048][2048]
    const float* D = (const float*)d_in[3];   // [512][2048]

    float* recon = (float*)d_out;
    float* zden  = (float*)d_out + (size_t)BATCH * INPUT_DIM;  // u scratch, then dense z

    int*   zidx = (int*)d_ws;
    float* zval = (float*)((char*)d_ws + (size_t)BATCH * KSP * 4);
    float* Dt   = (float*)((char*)d_ws + (size_t)2 * BATCH * KSP * 4);

    transpose_512x2048_kernel<<<dim3(CODE_DIM / 32, INPUT_DIM / 32), dim3(32, 8), 0, stream>>>(D, Dt);

    for (int l = 0; l < LAYERS; ++l) {
        const float* Wl = W + (size_t)l * INPUT_DIM * CODE_DIM;
        const float* Sl = (l == 0) ? nullptr : S + (size_t)l * CODE_DIM * CODE_DIM;
        gemm_layer_kernel<<<dim3(CODE_DIM / BN, BATCH / BM), 256, 0, stream>>>(
            x, Wl, Sl, (l == 0) ? nullptr : zidx, (l == 0) ? nullptr : zval, zden);
        topk32_wave_kernel<<<BATCH / 4, 256, 0, stream>>>(zden, zidx, zval);
    }

    zfill_scatter_kernel<<<BATCH / 8, 256, 0, stream>>>(zidx, zval, zden);
    recon_kernel<<<BATCH, 128, 0, stream>>>(zidx, zval, Dt, recon);
}

// Round 15
// 7661.237 us; speedup vs baseline: 5.3917x; 5.3917x over previous
//
#include <hip/hip_runtime.h>
#include <stdint.h>

#define LAYERS    5
#define INPUT_DIM 512
#define CODE_DIM  2048
#define BATCH     32768
#define KSP       32

#define BM  128
#define BN  128
#define BKT 16

#define GLOAD_LDS16(dst, src) \
    __builtin_amdgcn_global_load_lds((const __attribute__((address_space(1))) uint32_t*)(src), \
                                     (__attribute__((address_space(3))) uint32_t*)(dst), 16, 0, 0)

// ---------------------------------------------------------------------------
// D [512][2048] -> Dt [2048][512]  (bit copy)
__global__ __launch_bounds__(256) void transpose_512x2048_kernel(const float* __restrict__ src,
                                                                 float* __restrict__ dst)
{
    __shared__ float tile[32][33];
    const int tx = threadIdx.x;
    const int ty = threadIdx.y;
    const int cb = blockIdx.x * 32;
    const int ib = blockIdx.y * 32;
    #pragma unroll
    for (int j = 0; j < 32; j += 8)
        tile[ty + j][tx] = src[(size_t)(ib + ty + j) * CODE_DIM + cb + tx];
    __syncthreads();
    #pragma unroll
    for (int j = 0; j < 32; j += 8)
        dst[(size_t)(cb + ty + j) * INPUT_DIM + ib + tx] = tile[tx][ty + j];
}

// ---------------------------------------------------------------------------
// x [32768][512] -> xT [512][32768]  (bit copy)
__global__ __launch_bounds__(256) void transpose_x_kernel(const float* __restrict__ src,
                                                          float* __restrict__ dst)
{
    __shared__ float tile[32][33];
    const int tx = threadIdx.x;
    const int ty = threadIdx.y;
    const int cb = blockIdx.x * 32;   // col base in x (0..511)
    const int rb = blockIdx.y * 32;   // row base in x (0..32767)
    #pragma unroll
    for (int j = 0; j < 32; j += 8)
        tile[ty + j][tx] = src[(size_t)(rb + ty + j) * INPUT_DIM + cb + tx];
    __syncthreads();
    #pragma unroll
    for (int j = 0; j < 32; j += 8)
        dst[(size_t)(cb + ty + j) * BATCH + rb + tx] = tile[tx][ty + j];
}

// ---------------------------------------------------------------------------
// u = x@Wl (+ z@Sl for l>0).  Arithmetic contract (np/BLAS-faithful):
//  - x@W: one f32 accumulator per element, k = 0..511 strictly ascending fmaf
//  - z@S: separate zero-init accumulator, 32 nz folded ascending-index, fmaf
//  - u = xw + zs (single add)
// DOUBLE-BUFFERED, ZERO staging registers: A (from pre-transposed xT) and B
// both staged via global_load_lds.  Per tile: prefetch(buf^1) -> compute(buf)
// -> barrier (compiler vmcnt drain = load fence).
// r14 BUG FIX: each gload16 covers 2 rows (1 KB); BKT=16 needs 8 gloads per
// operand -> each wave stages 4 rows via 2 gloads (was 2 rows via 1 -> rows
// 8..15 were garbage, absmax 131).
// r13 lesson: register-held prefetch explodes regalloc; gload holds nothing.
// acc only compile-time-indexed (r5/r6/r7); static buffer indices (2x unroll).
__global__ __launch_bounds__(256) void gemm_xt_kernel(
    const float* __restrict__ xT, const float* __restrict__ Wl,
    const float* __restrict__ Sl, const int* __restrict__ zidx,
    const float* __restrict__ zval, float* __restrict__ u)
{
    __shared__ float As[2][BKT][BM];   // 16 KB, gload dest (linear)
    __shared__ float Bs[2][BKT][BN];   // 16 KB, gload dest (linear)

    const int t    = threadIdx.x;
    const int lane = t & 63;
    const int wid  = t >> 6;
    const int c0   = blockIdx.x * BN;
    const int r0   = blockIdx.y * BM;
    const int tm0  = (t >> 4) * 8;        // 8 rows
    const int cn   = (t & 15) * 4;        // col quads at cn, cn+64

    // staging: wave wid owns k-rows wid*4 .. wid*4+3 (2 gloads x 2 rows each)
    const int kr0  = wid * 4 + (lane >> 5);      // rows wid*4, wid*4+1
    const int kr2  = kr0 + 2;                    // rows wid*4+2, wid*4+3
    const int coff = (lane & 31) * 4;

#define GLOAD_TILE(B, KT)                                                     \
    GLOAD_LDS16(&As[B][wid * 4][0],                                           \
                xT + (size_t)((KT) + kr0) * BATCH + r0 + coff);               \
    GLOAD_LDS16(&As[B][wid * 4 + 2][0],                                       \
                xT + (size_t)((KT) + kr2) * BATCH + r0 + coff);               \
    GLOAD_LDS16(&Bs[B][wid * 4][0],                                           \
                Wl + (size_t)((KT) + kr0) * CODE_DIM + c0 + coff);            \
    GLOAD_LDS16(&Bs[B][wid * 4 + 2][0],                                       \
                Wl + (size_t)((KT) + kr2) * CODE_DIM + c0 + coff);

#define COMPUTE_TILE(B)                                                       \
    _Pragma("unroll")                                                         \
    for (int kk = 0; kk < BKT; ++kk) {                                        \
        float av[8], bv[8];                                                   \
        *(float4*)&av[0] = *(const float4*)&As[B][kk][tm0];                   \
        *(float4*)&av[4] = *(const float4*)&As[B][kk][tm0 + 4];               \
        *(float4*)&bv[0] = *(const float4*)&Bs[B][kk][cn];                    \
        *(float4*)&bv[4] = *(const float4*)&Bs[B][kk][cn + 64];               \
        _Pragma("unroll")                                                     \
        for (int i = 0; i < 8; ++i)                                           \
            _Pragma("unroll")                                                 \
            for (int j = 0; j < 8; ++j)                                       \
                acc[i][j] = fmaf(av[i], bv[j], acc[i][j]);                    \
    }

    float acc[8][8];
    #pragma unroll
    for (int i = 0; i < 8; ++i)
        #pragma unroll
        for (int j = 0; j < 8; ++j) acc[i][j] = 0.f;

    GLOAD_TILE(0, 0);
    __syncthreads();                       // tile 0 landed

    for (int kt = 0; kt < INPUT_DIM; kt += 2 * BKT) {
        GLOAD_TILE(1, kt + BKT);           // async prefetch, overlaps compute
        COMPUTE_TILE(0);
        __syncthreads();                   // compute(0) done + buf1 landed
        if (kt + 2 * BKT < INPUT_DIM) {
            GLOAD_TILE(0, kt + 2 * BKT);
        }
        COMPUTE_TILE(1);
        __syncthreads();                   // compute(1) done + buf0 landed
    }

#undef GLOAD_TILE
#undef COMPUTE_TILE

    if (Sl != nullptr) {
        #pragma unroll
        for (int i = 0; i < 8; ++i) {           // FULLY unrolled: acc[i] static
            const int r = r0 + tm0 + i;
            const int*   ip = zidx + (size_t)r * KSP;   // ascending code index
            const float* vp = zval + (size_t)r * KSP;
            float zacc[8];
            #pragma unroll
            for (int j = 0; j < 8; ++j) zacc[j] = 0.f;
            for (int k = 0; k < KSP; ++k) {     // runtime k only touches memory
                int   j = ip[k];
                float v = vp[k];
                const float* srow = Sl + (size_t)j * CODE_DIM + c0 + cn;
                float4 s0 = *(const float4*)&srow[0];
                float4 s1 = *(const float4*)&srow[64];
                zacc[0] = fmaf(v, s0.x, zacc[0]);
                zacc[1] = fmaf(v, s0.y, zacc[1]);
                zacc[2] = fmaf(v, s0.z, zacc[2]);
                zacc[3] = fmaf(v, s0.w, zacc[3]);
                zacc[4] = fmaf(v, s1.x, zacc[4]);
                zacc[5] = fmaf(v, s1.y, zacc[5]);
                zacc[6] = fmaf(v, s1.z, zacc[6]);
                zacc[7] = fmaf(v, s1.w, zacc[7]);
            }
            #pragma unroll
            for (int j = 0; j < 8; ++j)     // single add: u = xw + zs
                acc[i][j] = acc[i][j] + zacc[j];
        }
    }

    #pragma unroll
    for (int i = 0; i < 8; ++i) {
        float* up = u + (size_t)(r0 + tm0 + i) * CODE_DIM + c0 + cn;
        *(float4*)&up[0]  = make_float4(acc[i][0], acc[i][1], acc[i][2], acc[i][3]);
        *(float4*)&up[64] = make_float4(acc[i][4], acc[i][5], acc[i][6], acc[i][7]);
    }
}

// ---------------------------------------------------------------------------
// FALLBACK (ws too small for xT): exact r12 gemm (stable 92 VGPR, no spill)
__global__ __launch_bounds__(256) void gemm_layer_kernel(
    const float* __restrict__ x, const float* __restrict__ Wl,
    const float* __restrict__ Sl, const int* __restrict__ zidx,
    const float* __restrict__ zval, float* __restrict__ u)
{
    __shared__ float As[2 * BKT][BM + 4];
    __shared__ float Bs[2 * BKT][BN];

    const int t    = threadIdx.x;
    const int lane = t & 63;
    const int wid  = t >> 6;
    const int c0   = blockIdx.x * BN;
    const int r0   = blockIdx.y * BM;
    const int tm0  = (t >> 4) * 8;
    const int cn   = (t & 15) * 4;

    float acc[8][8];
    #pragma unroll
    for (int i = 0; i < 8; ++i)
        #pragma unroll
        for (int j = 0; j < 8; ++j) acc[i][j] = 0.f;

    for (int kt = 0; kt < INPUT_DIM; kt += 2 * BKT) {
        #pragma unroll
        for (int i = 0; i < 4; ++i) {
            int f   = t * 4 + i;
            int row = f >> 3, kq = f & 7;
            float4 v = *(const float4*)&x[(size_t)(r0 + row) * INPUT_DIM + kt + kq * 4];
            As[kq * 4 + 0][row] = v.x;
            As[kq * 4 + 1][row] = v.y;
            As[kq * 4 + 2][row] = v.z;
            As[kq * 4 + 3][row] = v.w;
        }
        #pragma unroll
        for (int s = 0; s < 4; ++s) {
            int r = wid * 8 + s * 2;
            GLOAD_LDS16(&Bs[r][0],
                        Wl + (size_t)(kt + r + (lane >> 5)) * CODE_DIM + c0 + (lane & 31) * 4);
        }
        __syncthreads();
        #pragma unroll
        for (int kk = 0; kk < 2 * BKT; ++kk) {
            float a[8], b[8];
            *(float4*)&a[0] = *(const float4*)&As[kk][tm0];
            *(float4*)&a[4] = *(const float4*)&As[kk][tm0 + 4];
            *(float4*)&b[0] = *(const float4*)&Bs[kk][cn];
            *(float4*)&b[4] = *(const float4*)&Bs[kk][cn + 64];
            #pragma unroll
            for (int i = 0; i < 8; ++i)
                #pragma unroll
                for (int j = 0; j < 8; ++j)
                    acc[i][j] = fmaf(a[i], b[j], acc[i][j]);
        }
        __syncthreads();
    }

    if (Sl != nullptr) {
        #pragma unroll
        for (int i = 0; i < 8; ++i) {
            const int r = r0 + tm0 + i;
            const int*   ip = zidx + (size_t)r * KSP;
            const float* vp = zval + (size_t)r * KSP;
            float zacc[8];
            #pragma unroll
            for (int j = 0; j < 8; ++j) zacc[j] = 0.f;
            for (int k = 0; k < KSP; ++k) {
                int   j = ip[k];
                float v = vp[k];
                const float* srow = Sl + (size_t)j * CODE_DIM + c0 + cn;
                float4 s0 = *(const float4*)&srow[0];
                float4 s1 = *(const float4*)&srow[64];
                zacc[0] = fmaf(v, s0.x, zacc[0]);
                zacc[1] = fmaf(v, s0.y, zacc[1]);
                zacc[2] = fmaf(v, s0.z, zacc[2]);
                zacc[3] = fmaf(v, s0.w, zacc[3]);
                zacc[4] = fmaf(v, s1.x, zacc[4]);
                zacc[5] = fmaf(v, s1.y, zacc[5]);
                zacc[6] = fmaf(v, s1.z, zacc[6]);
                zacc[7] = fmaf(v, s1.w, zacc[7]);
            }
            #pragma unroll
            for (int j = 0; j < 8; ++j)
                acc[i][j] = acc[i][j] + zacc[j];
        }
    }

    #pragma unroll
    for (int i = 0; i < 8; ++i) {
        float* up = u + (size_t)(r0 + tm0 + i) * CODE_DIM + c0 + cn;
        *(float4*)&up[0]  = make_float4(acc[i][0], acc[i][1], acc[i][2], acc[i][3]);
        *(float4*)&up[64] = make_float4(acc[i][4], acc[i][5], acc[i][6], acc[i][7]);
    }
}

// ---------------------------------------------------------------------------
// top-32 by |u| (desc, tie -> lower index), one WAVE per row, registers only.
// Key-only max tree + ballot owner-select; keys = (|u| bits)+1 (monotone,
// 0 = popped sentinel).  All register arrays statically indexed (rule #20).
__global__ __launch_bounds__(256) void topk32_wave_kernel(const float* __restrict__ u,
                                                          int* __restrict__ zidx,
                                                          float* __restrict__ zval)
{
    const int lane = threadIdx.x & 63;
    const int row  = blockIdx.x * 4 + (threadIdx.x >> 6);
    const float* ur = u + (size_t)row * CODE_DIM;

    uint32_t a[32];                       // lane's keys: global idx = lane*32 + j
    #pragma unroll
    for (int q = 0; q < 8; ++q) {
        float4 v = *(const float4*)&ur[lane * 32 + q * 4];
        a[q * 4 + 0] = (__float_as_uint(v.x) & 0x7fffffffu) + 1u;
        a[q * 4 + 1] = (__float_as_uint(v.y) & 0x7fffffffu) + 1u;
        a[q * 4 + 2] = (__float_as_uint(v.z) & 0x7fffffffu) + 1u;
        a[q * 4 + 3] = (__float_as_uint(v.w) & 0x7fffffffu) + 1u;
    }

    uint32_t wi = 0xFFFFFFFFu;            // slot-it winner gidx (lanes 0..31)
    for (int it = 0; it < KSP; ++it) {
        uint32_t t0[16], t1[8], t2[4], t3[2];
        #pragma unroll
        for (int j = 0; j < 16; ++j) t0[j] = a[2*j]  > a[2*j+1]  ? a[2*j]  : a[2*j+1];
        #pragma unroll
        for (int j = 0; j < 8;  ++j) t1[j] = t0[2*j] > t0[2*j+1] ? t0[2*j] : t0[2*j+1];
        #pragma unroll
        for (int j = 0; j < 4;  ++j) t2[j] = t1[2*j] > t1[2*j+1] ? t1[2*j] : t1[2*j+1];
        #pragma unroll
        for (int j = 0; j < 2;  ++j) t3[j] = t2[2*j] > t2[2*j+1] ? t2[2*j] : t2[2*j+1];
        const uint32_t mloc = t3[0] > t3[1] ? t3[0] : t3[1];

        uint32_t g = mloc;
        #pragma unroll
        for (int off = 1; off <= 32; off <<= 1) {
            uint32_t og = __shfl_xor(g, off);
            g = og > g ? og : g;
        }

        unsigned long long bal = __ballot(mloc == g);
        int owner = __ffsll(bal) - 1;

        int bj = 0;
        #pragma unroll
        for (int j = 31; j >= 0; --j)
            if (a[j] == g) bj = j;
        int bjo = __shfl(bj, owner);

        uint32_t gidx = (uint32_t)owner * 32u + (uint32_t)bjo;
        if (lane == it) wi = gidx;

        if (lane == owner) {
            #pragma unroll
            for (int j = 0; j < 32; ++j)
                if (j == bjo) a[j] = 0u;
        }
    }

    int rank = 0;
    #pragma unroll
    for (int m = 0; m < 32; ++m) {
        uint32_t om = __shfl(wi, m);
        rank += (om < wi) ? 1 : 0;
    }
    if (lane < KSP) {
        int idx = (int)wi;
        zidx[(size_t)row * KSP + rank] = idx;
        zval[(size_t)row * KSP + rank] = ur[idx];
    }
}

// ---------------------------------------------------------------------------
__global__ __launch_bounds__(256) void zfill_scatter_kernel(const int* __restrict__ zidx,
                                                            const float* __restrict__ zval,
                                                            float* __restrict__ zden)
{
    const int t  = threadIdx.x;
    const int r0 = blockIdx.x * 8;
    float* base = zden + (size_t)r0 * CODE_DIM;
    const float4 zero = make_float4(0.f, 0.f, 0.f, 0.f);
    for (int q = t; q < 8 * CODE_DIM / 4; q += 256)
        *(float4*)&base[q * 4] = zero;
    __syncthreads();
    const int rl = t >> 5, k = t & 31;
    int   idx = zidx[(size_t)(r0 + rl) * KSP + k];
    float v   = zval[(size_t)(r0 + rl) * KSP + k];
    base[(size_t)rl * CODE_DIM + idx] = v;
}

// ---------------------------------------------------------------------------
// recon: ascending-index fold of 32 nonzeros, f32 fmaf (np z@D.T faithful)
__global__ __launch_bounds__(128) void recon_kernel(const int* __restrict__ zidx,
                                                    const float* __restrict__ zval,
                                                    const float* __restrict__ Dt,
                                                    float* __restrict__ recon)
{
    const int t   = threadIdx.x;
    const int row = blockIdx.x;
    float4 acc = make_float4(0.f, 0.f, 0.f, 0.f);
    const int*   ip = zidx + (size_t)row * KSP;
    const float* vp = zval + (size_t)row * KSP;
    for (int k = 0; k < KSP; ++k) {
        int   j = ip[k];
        float v = vp[k];
        float4 d = *(const float4*)&Dt[(size_t)j * INPUT_DIM + t * 4];
        acc.x = fmaf(v, d.x, acc.x);
        acc.y = fmaf(v, d.y, acc.y);
        acc.z = fmaf(v, d.z, acc.z);
        acc.w = fmaf(v, d.w, acc.w);
    }
    *(float4*)&recon[(size_t)row * INPUT_DIM + t * 4] = acc;
}

// ---------------------------------------------------------------------------
extern "C" void kernel_launch(void* const* d_in, const int* in_sizes, int n_in,
                              void* d_out, int out_size, void* d_ws, size_t ws_size,
                              hipStream_t stream)
{
    const float* x = (const float*)d_in[0];
    const float* W = (const float*)d_in[1];   // [5][512][2048]
    const float* S = (const float*)d_in[2];   // [5][2048][2048]
    const float* D = (const float*)d_in[3];   // [512][2048]

    float* recon = (float*)d_out;
    float* zden  = (float*)d_out + (size_t)BATCH * INPUT_DIM;  // u scratch, then dense z

    int*   zidx = (int*)d_ws;
    float* zval = (float*)((char*)d_ws + (size_t)BATCH * KSP * 4);
    float* Dt   = (float*)((char*)d_ws + (size_t)2 * BATCH * KSP * 4);
    float* xT   = (float*)((char*)d_ws + (size_t)2 * BATCH * KSP * 4
                                       + (size_t)CODE_DIM * INPUT_DIM * 4);
    const size_t need_xt = (size_t)2 * BATCH * KSP * 4
                         + (size_t)CODE_DIM * INPUT_DIM * 4
                         + (size_t)BATCH * INPUT_DIM * 4;
    const bool use_xt = ws_size >= need_xt;

    transpose_512x2048_kernel<<<dim3(CODE_DIM / 32, INPUT_DIM / 32), dim3(32, 8), 0, stream>>>(D, Dt);
    if (use_xt)
        transpose_x_kernel<<<dim3(INPUT_DIM / 32, BATCH / 32), dim3(32, 8), 0, stream>>>(x, xT);

    for (int l = 0; l < LAYERS; ++l) {
        const float* Wl = W + (size_t)l * INPUT_DIM * CODE_DIM;
        const float* Sl = (l == 0) ? nullptr : S + (size_t)l * CODE_DIM * CODE_DIM;
        if (use_xt)
            gemm_xt_kernel<<<dim3(CODE_DIM / BN, BATCH / BM), 256, 0, stream>>>(
                xT, Wl, Sl, (l == 0) ? nullptr : zidx, (l == 0) ? nullptr : zval, zden);
        else
            gemm_layer_kernel<<<dim3(CODE_DIM / BN, BATCH / BM), 256, 0, stream>>>(
                x, Wl, Sl, (l == 0) ? nullptr : zidx, (l == 0) ? nullptr : zval, zden);
        topk32_wave_kernel<<<BATCH / 4, 256, 0, stream>>>(zden, zidx, zval);
    }

    zfill_scatter_kernel<<<BATCH / 8, 256, 0, stream>>>(zidx, zval, zden);
    recon_kernel<<<BATCH, 128, 0, stream>>>(zidx, zval, Dt, recon);
}

// Round 16
// 6725.236 us; speedup vs baseline: 6.1421x; 1.1392x over previous
//
#include <hip/hip_runtime.h>
#include <stdint.h>

#define LAYERS    5
#define INPUT_DIM 512
#define CODE_DIM  2048
#define BATCH     32768
#define KSP       32

#define BM   128
#define BN   128
#define BKT2 32

// ---------------------------------------------------------------------------
// D [512][2048] -> Dt [2048][512]  (bit copy)
__global__ __launch_bounds__(256) void transpose_512x2048_kernel(const float* __restrict__ src,
                                                                 float* __restrict__ dst)
{
    __shared__ float tile[32][33];
    const int tx = threadIdx.x;
    const int ty = threadIdx.y;
    const int cb = blockIdx.x * 32;
    const int ib = blockIdx.y * 32;
    #pragma unroll
    for (int j = 0; j < 32; j += 8)
        tile[ty + j][tx] = src[(size_t)(ib + ty + j) * CODE_DIM + cb + tx];
    __syncthreads();
    #pragma unroll
    for (int j = 0; j < 32; j += 8)
        dst[(size_t)(cb + ty + j) * INPUT_DIM + ib + tx] = tile[tx][ty + j];
}

// ---------------------------------------------------------------------------
// u = x@Wl (+ z@Sl for l>0).  Arithmetic contract (np/BLAS-faithful):
//  - x@W: one f32 accumulator per element, k = 0..511 strictly ascending fmaf
//  - z@S: separate zero-init accumulator, 32 nz folded ascending-index, fmaf
//  - u = xw + zs (single add)
// B-FROM-GLOBAL variant: only A is LDS-staged (halves LDS-pipe issue, the
// measured binding pipe of the r12 structure).  B quads are read straight
// from global in the inner loop — same pattern as the S-epilogue, which
// compiles spill-free at 92 VGPR.  W panels are L2-resident (4 MB/layer,
// HBM at 6%).  B values identical bits -> arithmetic chain unchanged.
// RULES (r5-r15 lessons): acc/zacc only compile-time-indexed; no staging
// registers held across compute; no dbuf (every variant lost to regalloc);
// partial unroll 4 on kk caps hoisted-load pressure.
__global__ __launch_bounds__(256) void gemm_layer_kernel(
    const float* __restrict__ x, const float* __restrict__ Wl,
    const float* __restrict__ Sl, const int* __restrict__ zidx,
    const float* __restrict__ zval, float* __restrict__ u)
{
    __shared__ float As[BKT2][BM + 4];   // transposed: As[k][m]; reads broadcast

    const int t   = threadIdx.x;
    const int c0  = blockIdx.x * BN;
    const int r0  = blockIdx.y * BM;
    const int tm0 = (t >> 4) * 8;         // 8 rows
    const int cn  = (t & 15) * 4;         // col quads at cn, cn+64

    float acc[8][8];
    #pragma unroll
    for (int i = 0; i < 8; ++i)
        #pragma unroll
        for (int j = 0; j < 8; ++j) acc[i][j] = 0.f;

    for (int kt = 0; kt < INPUT_DIM; kt += BKT2) {
        // --- stage A: 128 rows x 32 k, transposed into As[k][m] ---
        #pragma unroll
        for (int i = 0; i < 4; ++i) {
            int f   = t * 4 + i;          // 0..1023 float4s
            int row = f >> 3, kq = f & 7;
            float4 v = *(const float4*)&x[(size_t)(r0 + row) * INPUT_DIM + kt + kq * 4];
            As[kq * 4 + 0][row] = v.x;
            As[kq * 4 + 1][row] = v.y;
            As[kq * 4 + 2][row] = v.z;
            As[kq * 4 + 3][row] = v.w;
        }
        __syncthreads();

        const float* Wb = Wl + (size_t)kt * CODE_DIM + c0 + cn;  // tile B base
        #pragma unroll 4
        for (int kk = 0; kk < BKT2; ++kk) {   // strictly ascending k chain
            float av[8], bv[8];
            *(float4*)&av[0] = *(const float4*)&As[kk][tm0];
            *(float4*)&av[4] = *(const float4*)&As[kk][tm0 + 4];
            const float* brow = Wb + (size_t)kk * CODE_DIM;
            *(float4*)&bv[0] = *(const float4*)&brow[0];    // global (L1/L2 hit)
            *(float4*)&bv[4] = *(const float4*)&brow[64];
            #pragma unroll
            for (int i = 0; i < 8; ++i)
                #pragma unroll
                for (int j = 0; j < 8; ++j)
                    acc[i][j] = fmaf(av[i], bv[j], acc[i][j]);
        }
        __syncthreads();   // A tile consumed before next overwrite
    }

    if (Sl != nullptr) {
        #pragma unroll
        for (int i = 0; i < 8; ++i) {           // FULLY unrolled: acc[i] static
            const int r = r0 + tm0 + i;
            const int*   ip = zidx + (size_t)r * KSP;   // ascending code index
            const float* vp = zval + (size_t)r * KSP;
            float zacc[8];
            #pragma unroll
            for (int j = 0; j < 8; ++j) zacc[j] = 0.f;
            for (int k = 0; k < KSP; ++k) {     // runtime k only touches memory
                int   j = ip[k];
                float v = vp[k];
                const float* srow = Sl + (size_t)j * CODE_DIM + c0 + cn;
                float4 s0 = *(const float4*)&srow[0];
                float4 s1 = *(const float4*)&srow[64];
                zacc[0] = fmaf(v, s0.x, zacc[0]);
                zacc[1] = fmaf(v, s0.y, zacc[1]);
                zacc[2] = fmaf(v, s0.z, zacc[2]);
                zacc[3] = fmaf(v, s0.w, zacc[3]);
                zacc[4] = fmaf(v, s1.x, zacc[4]);
                zacc[5] = fmaf(v, s1.y, zacc[5]);
                zacc[6] = fmaf(v, s1.z, zacc[6]);
                zacc[7] = fmaf(v, s1.w, zacc[7]);
            }
            #pragma unroll
            for (int j = 0; j < 8; ++j)     // single add: u = xw + zs
                acc[i][j] = acc[i][j] + zacc[j];
        }
    }

    #pragma unroll
    for (int i = 0; i < 8; ++i) {
        float* up = u + (size_t)(r0 + tm0 + i) * CODE_DIM + c0 + cn;
        *(float4*)&up[0]  = make_float4(acc[i][0], acc[i][1], acc[i][2], acc[i][3]);
        *(float4*)&up[64] = make_float4(acc[i][4], acc[i][5], acc[i][6], acc[i][7]);
    }
}

// ---------------------------------------------------------------------------
// top-32 by |u| (desc, tie -> lower index), one WAVE per row, registers only.
// Key-only max tree + ballot owner-select; keys = (|u| bits)+1 (monotone,
// 0 = popped sentinel).  All register arrays statically indexed (rule #20).
__global__ __launch_bounds__(256) void topk32_wave_kernel(const float* __restrict__ u,
                                                          int* __restrict__ zidx,
                                                          float* __restrict__ zval)
{
    const int lane = threadIdx.x & 63;
    const int row  = blockIdx.x * 4 + (threadIdx.x >> 6);
    const float* ur = u + (size_t)row * CODE_DIM;

    uint32_t a[32];                       // lane's keys: global idx = lane*32 + j
    #pragma unroll
    for (int q = 0; q < 8; ++q) {
        float4 v = *(const float4*)&ur[lane * 32 + q * 4];
        a[q * 4 + 0] = (__float_as_uint(v.x) & 0x7fffffffu) + 1u;
        a[q * 4 + 1] = (__float_as_uint(v.y) & 0x7fffffffu) + 1u;
        a[q * 4 + 2] = (__float_as_uint(v.z) & 0x7fffffffu) + 1u;
        a[q * 4 + 3] = (__float_as_uint(v.w) & 0x7fffffffu) + 1u;
    }

    uint32_t wi = 0xFFFFFFFFu;            // slot-it winner gidx (lanes 0..31)
    for (int it = 0; it < KSP; ++it) {
        uint32_t t0[16], t1[8], t2[4], t3[2];
        #pragma unroll
        for (int j = 0; j < 16; ++j) t0[j] = a[2*j]  > a[2*j+1]  ? a[2*j]  : a[2*j+1];
        #pragma unroll
        for (int j = 0; j < 8;  ++j) t1[j] = t0[2*j] > t0[2*j+1] ? t0[2*j] : t0[2*j+1];
        #pragma unroll
        for (int j = 0; j < 4;  ++j) t2[j] = t1[2*j] > t1[2*j+1] ? t1[2*j] : t1[2*j+1];
        #pragma unroll
        for (int j = 0; j < 2;  ++j) t3[j] = t2[2*j] > t2[2*j+1] ? t2[2*j] : t2[2*j+1];
        const uint32_t mloc = t3[0] > t3[1] ? t3[0] : t3[1];

        uint32_t g = mloc;
        #pragma unroll
        for (int off = 1; off <= 32; off <<= 1) {
            uint32_t og = __shfl_xor(g, off);
            g = og > g ? og : g;
        }

        unsigned long long bal = __ballot(mloc == g);
        int owner = __ffsll(bal) - 1;

        int bj = 0;
        #pragma unroll
        for (int j = 31; j >= 0; --j)
            if (a[j] == g) bj = j;
        int bjo = __shfl(bj, owner);

        uint32_t gidx = (uint32_t)owner * 32u + (uint32_t)bjo;
        if (lane == it) wi = gidx;

        if (lane == owner) {
            #pragma unroll
            for (int j = 0; j < 32; ++j)
                if (j == bjo) a[j] = 0u;
        }
    }

    int rank = 0;
    #pragma unroll
    for (int m = 0; m < 32; ++m) {
        uint32_t om = __shfl(wi, m);
        rank += (om < wi) ? 1 : 0;
    }
    if (lane < KSP) {
        int idx = (int)wi;
        zidx[(size_t)row * KSP + rank] = idx;
        zval[(size_t)row * KSP + rank] = ur[idx];
    }
}

// ---------------------------------------------------------------------------
__global__ __launch_bounds__(256) void zfill_scatter_kernel(const int* __restrict__ zidx,
                                                            const float* __restrict__ zval,
                                                            float* __restrict__ zden)
{
    const int t  = threadIdx.x;
    const int r0 = blockIdx.x * 8;
    float* base = zden + (size_t)r0 * CODE_DIM;
    const float4 zero = make_float4(0.f, 0.f, 0.f, 0.f);
    for (int q = t; q < 8 * CODE_DIM / 4; q += 256)
        *(float4*)&base[q * 4] = zero;
    __syncthreads();
    const int rl = t >> 5, k = t & 31;
    int   idx = zidx[(size_t)(r0 + rl) * KSP + k];
    float v   = zval[(size_t)(r0 + rl) * KSP + k];
    base[(size_t)rl * CODE_DIM + idx] = v;
}

// ---------------------------------------------------------------------------
// recon: ascending-index fold of 32 nonzeros, f32 fmaf (np z@D.T faithful)
__global__ __launch_bounds__(128) void recon_kernel(const int* __restrict__ zidx,
                                                    const float* __restrict__ zval,
                                                    const float* __restrict__ Dt,
                                                    float* __restrict__ recon)
{
    const int t   = threadIdx.x;
    const int row = blockIdx.x;
    float4 acc = make_float4(0.f, 0.f, 0.f, 0.f);
    const int*   ip = zidx + (size_t)row * KSP;
    const float* vp = zval + (size_t)row * KSP;
    for (int k = 0; k < KSP; ++k) {
        int   j = ip[k];
        float v = vp[k];
        float4 d = *(const float4*)&Dt[(size_t)j * INPUT_DIM + t * 4];
        acc.x = fmaf(v, d.x, acc.x);
        acc.y = fmaf(v, d.y, acc.y);
        acc.z = fmaf(v, d.z, acc.z);
        acc.w = fmaf(v, d.w, acc.w);
    }
    *(float4*)&recon[(size_t)row * INPUT_DIM + t * 4] = acc;
}

// ---------------------------------------------------------------------------
extern "C" void kernel_launch(void* const* d_in, const int* in_sizes, int n_in,
                              void* d_out, int out_size, void* d_ws, size_t ws_size,
                              hipStream_t stream)
{
    const float* x = (const float*)d_in[0];
    const float* W = (const float*)d_in[1];   // [5][512][2048]
    const float* S = (const float*)d_in[2];   // [5][2048][2048]
    const float* D = (const float*)d_in[3];   // [512][2048]

    float* recon = (float*)d_out;
    float* zden  = (float*)d_out + (size_t)BATCH * INPUT_DIM;  // u scratch, then dense z

    int*   zidx = (int*)d_ws;
    float* zval = (float*)((char*)d_ws + (size_t)BATCH * KSP * 4);
    float* Dt   = (float*)((char*)d_ws + (size_t)2 * BATCH * KSP * 4);

    transpose_512x2048_kernel<<<dim3(CODE_DIM / 32, INPUT_DIM / 32), dim3(32, 8), 0, stream>>>(D, Dt);

    for (int l = 0; l < LAYERS; ++l) {
        const float* Wl = W + (size_t)l * INPUT_DIM * CODE_DIM;
        const float* Sl = (l == 0) ? nullptr : S + (size_t)l * CODE_DIM * CODE_DIM;
        gemm_layer_kernel<<<dim3(CODE_DIM / BN, BATCH / BM), 256, 0, stream>>>(
            x, Wl, Sl, (l == 0) ? nullptr : zidx, (l == 0) ? nullptr : zval, zden);
        topk32_wave_kernel<<<BATCH / 4, 256, 0, stream>>>(zden, zidx, zval);
    }

    zfill_scatter_kernel<<<BATCH / 8, 256, 0, stream>>>(zidx, zval, zden);
    recon_kernel<<<BATCH, 128, 0, stream>>>(zidx, zval, Dt, recon);
}